// Round 1
// baseline (3887.542 us; speedup 1.0000x reference)
//
#include <hip/hip_runtime.h>

// B=1024, L=256, F=128, H=256, 3H=768, A=128, CH=256, OUT=512
#define B_ 1024
#define L_ 256
#define F_ 128
#define H_ 256

typedef __bf16 bf16x8 __attribute__((ext_vector_type(8)));
typedef float f32x4 __attribute__((ext_vector_type(4)));

#define MFMA16(a, b, c) __builtin_amdgcn_mfma_f32_16x16x32_bf16((a), (b), (c), 0, 0, 0)

__device__ __forceinline__ float sigm(float x) { return 1.f / (1.f + __expf(-x)); }
__device__ __forceinline__ float tanh_f(float x) {
  float ax = fabsf(x);
  float e = __expf(-2.f * ax);          // in (0,1], no overflow
  float r = (1.f - e) / (1.f + e);
  return copysignf(r, x);
}
__device__ __forceinline__ bf16x8 ld8(const __bf16* p) { return *(const bf16x8*)p; }

// ---- weight conversion: f32 -> bf16 (Wa also transposed to [A][H]) ----
__global__ void cvt_kernel(const float* __restrict__ wih_f, const float* __restrict__ whh_f,
                           const float* __restrict__ wout_f, const float* __restrict__ wa_f,
                           __bf16* __restrict__ wih, __bf16* __restrict__ whh,
                           __bf16* __restrict__ wout, __bf16* __restrict__ wa_t) {
  int i = blockIdx.x * 256 + threadIdx.x;
  if (i < 98304) wih[i] = (__bf16)wih_f[i];                          // [768][128]
  else if (i < 294912) whh[i - 98304] = (__bf16)whh_f[i - 98304];    // [768][256]
  else if (i < 327680) wout[i - 294912] = (__bf16)wout_f[i - 294912]; // [128][256]
  else if (i < 360448) {                                             // Wa[k][a] -> wa_t[a][k]
    int j = i - 327680;
    int a = j >> 8, k = j & 255;
    wa_t[j] = (__bf16)wa_f[k * 128 + a];
  }
}

// ---- fused GRU recurrence + out-projection + hidden store ----
// 64 blocks x 512 threads (8 waves). Block owns 16 batch rows.
// Wave w owns H-columns [w*32, w*32+32) for all three gates -> gate math is wave-local.
// h double-buffered in LDS (bf16, padded rows). 1 barrier per step:
//   P1: MFMA gi(x_t)+gh(h_t) (register A-frags)  P2: gates, read h_old buf[p], write h_{t+1} buf[p^1]
//   BAR  P4: re-read h_{t+1} frags (kept for next gh), out-proj MFMA, masked stores.
__global__ __launch_bounds__(512, 2) void gru_kernel(
    const float* __restrict__ x, const int* __restrict__ tte,
    const float* __restrict__ b_ih, const float* __restrict__ b_hh,
    const float* __restrict__ b_out,
    const __bf16* __restrict__ wih, const __bf16* __restrict__ whh,
    const __bf16* __restrict__ wout,
    __bf16* __restrict__ hid, float* __restrict__ out) {
  __shared__ __bf16 hbuf[2][16][264];   // +8 pad: row stride 132 dwords -> conflict-light
  const int tid = threadIdx.x;
  const int lane = tid & 63;
  const int w = tid >> 6;
  const int b0 = blockIdx.x * 16;
  const int l15 = lane & 15;
  const int lg = lane >> 4;
  const int kofs = lg * 8;

  for (int i = tid; i < 2 * 16 * 264; i += 512) ((__bf16*)hbuf)[i] = (__bf16)0.f;

  float br[2], bz[2], bi_n[2], bh_n[2];
#pragma unroll
  for (int hf = 0; hf < 2; ++hf) {
    int c = w * 32 + hf * 16 + l15;
    br[hf] = b_ih[c] + b_hh[c];
    bz[hf] = b_ih[256 + c] + b_hh[256 + c];
    bi_n[hf] = b_ih[512 + c];
    bh_n[hf] = b_hh[512 + c];
  }
  const float bo = b_out[w * 16 + l15];
  int tteC[4];
#pragma unroll
  for (int r = 0; r < 4; ++r) tteC[r] = tte[b0 + 4 * lg + r];
  const int tteS = tte[b0 + (tid >> 5)];
  int tmax = 0;
  for (int i = 0; i < 16; ++i) tmax = max(tmax, tte[b0 + i]);

  // loop-invariant weight-fragment base pointers (B-operand: col = l&15, k contiguous)
  const __bf16* wih_p[6];
  const __bf16* whh_p[6];
#pragma unroll
  for (int g = 0; g < 3; ++g)
#pragma unroll
    for (int hf = 0; hf < 2; ++hf) {
      int col = g * 256 + w * 32 + hf * 16 + l15;
      wih_p[g * 2 + hf] = wih + (size_t)col * 128 + kofs;
      whh_p[g * 2 + hf] = whh + (size_t)col * 256 + kofs;
    }
  const __bf16* wout_p = wout + (size_t)(w * 16 + l15) * 256 + kofs;

  bf16x8 hfr[8];
#pragma unroll
  for (int kt = 0; kt < 8; ++kt)
#pragma unroll
    for (int j = 0; j < 8; ++j) hfr[kt][j] = (__bf16)0.f;

  __syncthreads();

#pragma unroll 1
  for (int t = 0; t < tmax; ++t) {
    const int p = t & 1;
    // x_t A-fragments (f32 -> bf16)
    const float* xb = x + ((size_t)(b0 + l15) * L_ + t) * F_ + kofs;
    bf16x8 xfr[4];
#pragma unroll
    for (int kt = 0; kt < 4; ++kt) {
      float4 a = *(const float4*)(xb + kt * 32);
      float4 b = *(const float4*)(xb + kt * 32 + 4);
      xfr[kt][0] = (__bf16)a.x; xfr[kt][1] = (__bf16)a.y;
      xfr[kt][2] = (__bf16)a.z; xfr[kt][3] = (__bf16)a.w;
      xfr[kt][4] = (__bf16)b.x; xfr[kt][5] = (__bf16)b.y;
      xfr[kt][6] = (__bf16)b.z; xfr[kt][7] = (__bf16)b.w;
    }
    f32x4 accr0 = {0,0,0,0}, accr1 = {0,0,0,0};
    f32x4 accz0 = {0,0,0,0}, accz1 = {0,0,0,0};
    f32x4 acci0 = {0,0,0,0}, acci1 = {0,0,0,0};   // i_n (x-side only)
    f32x4 acch0 = {0,0,0,0}, acch1 = {0,0,0,0};   // h_n (h-side only)
    // gi: x_t @ W_ih^T (K=128)
#pragma unroll
    for (int kt = 0; kt < 4; ++kt) {
      accr0 = MFMA16(xfr[kt], ld8(wih_p[0] + kt * 32), accr0);
      accr1 = MFMA16(xfr[kt], ld8(wih_p[1] + kt * 32), accr1);
      accz0 = MFMA16(xfr[kt], ld8(wih_p[2] + kt * 32), accz0);
      accz1 = MFMA16(xfr[kt], ld8(wih_p[3] + kt * 32), accz1);
      acci0 = MFMA16(xfr[kt], ld8(wih_p[4] + kt * 32), acci0);
      acci1 = MFMA16(xfr[kt], ld8(wih_p[5] + kt * 32), acci1);
    }
    // gh: h_t @ W_hh^T (K=256); r,z share accumulators with gi
#pragma unroll
    for (int kt = 0; kt < 8; ++kt) {
      accr0 = MFMA16(hfr[kt], ld8(whh_p[0] + kt * 32), accr0);
      accr1 = MFMA16(hfr[kt], ld8(whh_p[1] + kt * 32), accr1);
      accz0 = MFMA16(hfr[kt], ld8(whh_p[2] + kt * 32), accz0);
      accz1 = MFMA16(hfr[kt], ld8(whh_p[3] + kt * 32), accz1);
      acch0 = MFMA16(hfr[kt], ld8(whh_p[4] + kt * 32), acch0);
      acch1 = MFMA16(hfr[kt], ld8(whh_p[5] + kt * 32), acch1);
    }
    // gates + h update (C-layout: row = 4*lg+r, col = tilebase + l15)
#pragma unroll
    for (int hf = 0; hf < 2; ++hf) {
      const f32x4 ar = hf ? accr1 : accr0;
      const f32x4 az = hf ? accz1 : accz0;
      const f32x4 ai = hf ? acci1 : acci0;
      const f32x4 ah = hf ? acch1 : acch0;
      const int colL = w * 32 + hf * 16 + l15;
#pragma unroll
      for (int r = 0; r < 4; ++r) {
        const int row = 4 * lg + r;
        float rg = sigm(ar[r] + br[hf]);
        float zg = sigm(az[r] + bz[hf]);
        float ng = tanh_f(ai[r] + bi_n[hf] + rg * (ah[r] + bh_n[hf]));
        float hold = (float)hbuf[p][row][colL];
        float hnew = zg * (hold - ng) + ng;
        float hw = (t < tteC[r]) ? hnew : hold;   // freeze past tte
        hbuf[p ^ 1][row][colL] = (__bf16)hw;
      }
    }
    __syncthreads();   // writes of h_{t+1} -> visible; also fences next-step buf reuse
    // out-projection from h_{t+1}; A-frags kept for next step's gh
    f32x4 acco = {0,0,0,0};
#pragma unroll
    for (int kt = 0; kt < 8; ++kt) {
      hfr[kt] = *(const bf16x8*)&hbuf[p ^ 1][l15][kt * 32 + kofs];
      acco = MFMA16(hfr[kt], ld8(wout_p + kt * 32), acco);
    }
#pragma unroll
    for (int r = 0; r < 4; ++r) {
      const int row = 4 * lg + r;
      if (t < tteC[r])
        out[((size_t)(b0 + row) * L_ + t) * F_ + w * 16 + l15] = acco[r] + bo;
    }
    // hidden store (active rows only; inactive pre-zeroed by memset)
    {
      const int row = tid >> 5, seg = tid & 31;
      if (t < tteS) {
        uint4 v = *(const uint4*)&hbuf[p ^ 1][row][seg * 8];
        *(uint4*)(hid + ((size_t)(b0 + row) * L_ + t) * H_ + seg * 8) = v;
      }
    }
  }
}

// ---- decoder: attention (MFMA scores), softmax, context, MLP, final softmax ----
// one block per batch row; zero hidden rows (t>=tte) naturally give the constant score.
__global__ __launch_bounds__(256, 2) void decoder_kernel(
    const float* __restrict__ x, const int* __restrict__ tte,
    const __bf16* __restrict__ hid, const __bf16* __restrict__ wa_t,
    const float* __restrict__ va, const float* __restrict__ Ua,
    const float* __restrict__ W1, const float* __restrict__ b1,
    const float* __restrict__ W2, const float* __restrict__ b2,
    float* __restrict__ fht) {
  __shared__ float last_s[128], u_s[128], s_s[256], alpha_s[256], ctx_s[256], z1_s[256], f512[512];
  const int tid = threadIdx.x;
  const int b = blockIdx.x;
  const int tb = tte[b];
  if (tid < 128) last_s[tid] = x[((size_t)b * L_ + tb) * F_ + tid];
  __syncthreads();
  if (tid < 128) {
    float a = 0.f;
    for (int f = 0; f < 128; ++f) a += last_s[f] * Ua[f * 128 + tid];
    u_s[tid] = a;
  }
  __syncthreads();
  const int lane = tid & 63, w = tid >> 6, l15 = lane & 15, lg = lane >> 4, kofs = lg * 8;
#pragma unroll 1
  for (int mi = 0; mi < 4; ++mi) {
    const int mtile = w * 4 + mi;
    const int trow = mtile * 16 + l15;
    f32x4 sacc[8];
#pragma unroll
    for (int ct = 0; ct < 8; ++ct) { sacc[ct][0] = 0; sacc[ct][1] = 0; sacc[ct][2] = 0; sacc[ct][3] = 0; }
#pragma unroll
    for (int kt = 0; kt < 8; ++kt) {
      bf16x8 af = *(const bf16x8*)&hid[((size_t)b * L_ + trow) * H_ + kt * 32 + kofs];
#pragma unroll
      for (int ct = 0; ct < 8; ++ct) {
        bf16x8 bf = *(const bf16x8*)&wa_t[(size_t)(ct * 16 + l15) * 256 + kt * 32 + kofs];
        sacc[ct] = MFMA16(af, bf, sacc[ct]);
      }
    }
    float sp[4] = {0, 0, 0, 0};
#pragma unroll
    for (int ct = 0; ct < 8; ++ct) {
      int a = ct * 16 + l15;
      float ua = u_s[a], vv = va[a];
#pragma unroll
      for (int r = 0; r < 4; ++r) sp[r] += tanh_f(sacc[ct][r] + ua) * vv;
    }
#pragma unroll
    for (int r = 0; r < 4; ++r) {
      sp[r] += __shfl_xor(sp[r], 1);
      sp[r] += __shfl_xor(sp[r], 2);
      sp[r] += __shfl_xor(sp[r], 4);
      sp[r] += __shfl_xor(sp[r], 8);
    }
    if (l15 == 0) {
#pragma unroll
      for (int r = 0; r < 4; ++r) s_s[mtile * 16 + 4 * lg + r] = sp[r];
    }
  }
  __syncthreads();
  float m = -1e30f;
  for (int i = 0; i < 256; ++i) m = fmaxf(m, s_s[i]);
  float e = __expf(s_s[tid] - m);
  alpha_s[tid] = e;
  __syncthreads();
  float den = 0.f;
  for (int i = 0; i < 256; ++i) den += alpha_s[i];
  const float inv = 1.f / den;
  float cacc = 0.f;
  for (int t = 0; t < 256; ++t)
    cacc += alpha_s[t] * (float)hid[((size_t)b * L_ + t) * H_ + tid];
  ctx_s[tid] = cacc * inv;
  __syncthreads();
  float a1 = b1[tid];
  for (int k = 0; k < 256; ++k) a1 += ctx_s[k] * W1[k * 256 + tid];
  for (int k = 0; k < 128; ++k) a1 += last_s[k] * W1[(256 + k) * 256 + tid];
  z1_s[tid] = fmaxf(a1, 0.f);
  __syncthreads();
  float o0 = b2[tid], o1 = b2[tid + 256];
  for (int k = 0; k < 256; ++k) {
    float zv = z1_s[k];
    o0 += zv * W2[k * 512 + tid];
    o1 += zv * W2[k * 512 + tid + 256];
  }
  f512[tid] = o0; f512[tid + 256] = o1;
  __syncthreads();
  float m2 = -1e30f;
  for (int i = 0; i < 512; ++i) m2 = fmaxf(m2, f512[i]);
  __syncthreads();
  float e0 = __expf(o0 - m2), e1 = __expf(o1 - m2);
  f512[tid] = e0; f512[tid + 256] = e1;
  __syncthreads();
  float d2 = 0.f;
  for (int i = 0; i < 512; ++i) d2 += f512[i];
  const float inv2 = 1.f / d2;
  fht[(size_t)b * 512 + tid] = e0 * inv2;
  fht[(size_t)b * 512 + tid + 256] = e1 * inv2;
}

extern "C" void kernel_launch(void* const* d_in, const int* in_sizes, int n_in,
                              void* d_out, int out_size, void* d_ws, size_t ws_size,
                              hipStream_t stream) {
  const float* x = (const float*)d_in[0];
  const int* tte = (const int*)d_in[1];
  const float* W_ih = (const float*)d_in[2];
  const float* W_hh = (const float*)d_in[3];
  const float* b_ih = (const float*)d_in[4];
  const float* b_hh = (const float*)d_in[5];
  const float* W_out = (const float*)d_in[6];
  const float* b_out = (const float*)d_in[7];
  const float* Wa = (const float*)d_in[8];
  const float* Ua = (const float*)d_in[9];
  const float* va = (const float*)d_in[10];
  const float* W1 = (const float*)d_in[11];
  const float* b1 = (const float*)d_in[12];
  const float* W2 = (const float*)d_in[13];
  const float* b2 = (const float*)d_in[14];

  char* ws = (char*)d_ws;
  __bf16* wih = (__bf16*)(ws + 0);         // 768*128*2  = 196608
  __bf16* whh = (__bf16*)(ws + 196608);    // 768*256*2  = 393216
  __bf16* wout = (__bf16*)(ws + 589824);   // 128*256*2  = 65536
  __bf16* wa_t = (__bf16*)(ws + 655360);   // 128*256*2  = 65536
  __bf16* hid = (__bf16*)(ws + 1048576);   // 1024*256*256*2 = 134217728

  float* out = (float*)d_out;
  float* fht = out + (size_t)33554432;

  hipMemsetAsync(d_out, 0, (size_t)out_size * 4, stream);          // zero-padded outputs
  hipMemsetAsync(hid, 0, (size_t)134217728, stream);               // zero hidden past tte
  cvt_kernel<<<1408, 256, 0, stream>>>(W_ih, W_hh, W_out, Wa, wih, whh, wout, wa_t);
  gru_kernel<<<64, 512, 0, stream>>>(x, tte, b_ih, b_hh, b_out, wih, whh, wout, hid, out);
  decoder_kernel<<<1024, 256, 0, stream>>>(x, tte, hid, wa_t, va, Ua, W1, b1, W2, b2, fht);
}

// Round 2
// 1364.849 us; speedup vs baseline: 2.8483x; 2.8483x over previous
//
#include <hip/hip_runtime.h>

// B=1024, L=256, F=128, H=256, 3H=768, A=128, CH=256, OUT=512
#define B_ 1024
#define L_ 256
#define F_ 128
#define H_ 256

typedef __bf16 bf16x8 __attribute__((ext_vector_type(8)));
typedef __bf16 bf16x4 __attribute__((ext_vector_type(4)));
typedef float f32x4 __attribute__((ext_vector_type(4)));

#define MFMA16(a, b, c) __builtin_amdgcn_mfma_f32_16x16x32_bf16((a), (b), (c), 0, 0, 0)

__device__ __forceinline__ float sigm(float x) { return 1.f / (1.f + __expf(-x)); }
__device__ __forceinline__ float tanh_f(float x) {
  float ax = fabsf(x);
  float e = __expf(-2.f * ax);
  float r = (1.f - e) / (1.f + e);
  return copysignf(r, x);
}
__device__ __forceinline__ bf16x8 ld8(const __bf16* p) { return *(const bf16x8*)p; }

// ---- weight conversion: f32 -> bf16 (Wa also transposed to [A][H]) ----
__global__ void cvt_kernel(const float* __restrict__ wih_f, const float* __restrict__ whh_f,
                           const float* __restrict__ wout_f, const float* __restrict__ wa_f,
                           __bf16* __restrict__ wih, __bf16* __restrict__ whh,
                           __bf16* __restrict__ wout, __bf16* __restrict__ wa_t) {
  int i = blockIdx.x * 256 + threadIdx.x;
  if (i < 98304) wih[i] = (__bf16)wih_f[i];                           // [768][128]
  else if (i < 294912) whh[i - 98304] = (__bf16)whh_f[i - 98304];     // [768][256]
  else if (i < 327680) wout[i - 294912] = (__bf16)wout_f[i - 294912]; // [128][256]
  else if (i < 360448) {                                              // Wa[k][a] -> wa_t[a][k]
    int j = i - 327680;
    int a = j >> 8, k = j & 255;
    wa_t[j] = (__bf16)wa_f[k * 128 + a];
  }
}

// ---- gi precompute: gi[b,t,:] = x[b,t]@W_ih^T (+ folded biases), bf16,
// stored in MFMA C-fragment layout: chunk = ((t*64+bblk)*8+w)*6+tile,
// within chunk: (lg*16+l15)*4 + r  (4 rows per lane, 8B coalesced). ----
__global__ __launch_bounds__(512, 2) void gi_gemm_kernel(
    const float* __restrict__ x, const float* __restrict__ b_ih,
    const float* __restrict__ b_hh, const __bf16* __restrict__ wih,
    __bf16* __restrict__ gi) {
  const int tid = threadIdx.x;
  const int lane = tid & 63, w = tid >> 6;
  const int l15 = lane & 15, lg = lane >> 4, kofs = lg * 8;
  const int bblk = blockIdx.x & 63, tgrp = blockIdx.x >> 6;
  const int b0 = bblk * 16;

  bf16x8 wf[6][4];
  float bias[6];
#pragma unroll
  for (int tile = 0; tile < 6; ++tile) {
    const int gate = tile >> 1;
    const int c = w * 32 + (tile & 1) * 16 + l15;
    const int col = gate * 256 + c;
#pragma unroll
    for (int kt = 0; kt < 4; ++kt) wf[tile][kt] = ld8(wih + (size_t)col * 128 + kt * 32 + kofs);
    bias[tile] = (gate == 0) ? b_ih[c] + b_hh[c]
               : (gate == 1) ? b_ih[256 + c] + b_hh[256 + c]
                             : b_ih[512 + c];
  }

#pragma unroll 1
  for (int ti = 0; ti < 16; ++ti) {
    const int t = tgrp * 16 + ti;
    const float* xb = x + ((size_t)(b0 + l15) * L_ + t) * F_ + kofs;
    bf16x8 xfr[4];
#pragma unroll
    for (int kt = 0; kt < 4; ++kt) {
      float4 a = *(const float4*)(xb + kt * 32);
      float4 b = *(const float4*)(xb + kt * 32 + 4);
      xfr[kt][0] = (__bf16)a.x; xfr[kt][1] = (__bf16)a.y;
      xfr[kt][2] = (__bf16)a.z; xfr[kt][3] = (__bf16)a.w;
      xfr[kt][4] = (__bf16)b.x; xfr[kt][5] = (__bf16)b.y;
      xfr[kt][6] = (__bf16)b.z; xfr[kt][7] = (__bf16)b.w;
    }
    f32x4 acc[6];
#pragma unroll
    for (int tile = 0; tile < 6; ++tile) {
      acc[tile][0] = bias[tile]; acc[tile][1] = bias[tile];
      acc[tile][2] = bias[tile]; acc[tile][3] = bias[tile];
    }
#pragma unroll
    for (int kt = 0; kt < 4; ++kt)
#pragma unroll
      for (int tile = 0; tile < 6; ++tile)
        acc[tile] = MFMA16(xfr[kt], wf[tile][kt], acc[tile]);

    const size_t chunk = (((size_t)t * 64 + bblk) * 8 + w) * 6;
#pragma unroll
    for (int tile = 0; tile < 6; ++tile) {
      bf16x4 pk;
      pk[0] = (__bf16)acc[tile][0]; pk[1] = (__bf16)acc[tile][1];
      pk[2] = (__bf16)acc[tile][2]; pk[3] = (__bf16)acc[tile][3];
      *(bf16x4*)(gi + (chunk + tile) * 256 + (lg * 16 + l15) * 4) = pk;
    }
  }
}

// ---- recurrence: W_hh fully register-resident (48 bf16x8 = 192 VGPR/lane).
// 64 blocks x 512 threads; block owns 16 batch rows; wave w owns h-cols
// [w*32,w*32+32) -> 6 gate col-tiles {r,z,n}x{hf0,hf1}. 1 barrier/step. ----
__global__ __launch_bounds__(512, 2) void gru2_kernel(
    const int* __restrict__ tte, const float* __restrict__ b_hh,
    const __bf16* __restrict__ whh, const __bf16* __restrict__ gi,
    __bf16* __restrict__ hid) {
  __shared__ __bf16 hbuf[2][16][264];
  const int tid = threadIdx.x;
  const int lane = tid & 63, w = tid >> 6;
  const int l15 = lane & 15, lg = lane >> 4, kofs = lg * 8;
  const int b0 = blockIdx.x * 16;

  for (int i = tid; i < 2 * 16 * 264; i += 512) ((__bf16*)hbuf)[i] = (__bf16)0.f;

  bf16x8 wfr[6][8];
#pragma unroll
  for (int tile = 0; tile < 6; ++tile) {
    const int col = (tile >> 1) * 256 + w * 32 + (tile & 1) * 16 + l15;
#pragma unroll
    for (int kt = 0; kt < 8; ++kt) wfr[tile][kt] = ld8(whh + (size_t)col * 256 + kt * 32 + kofs);
  }
  float bhn[2];
#pragma unroll
  for (int hf = 0; hf < 2; ++hf) bhn[hf] = b_hh[512 + w * 32 + hf * 16 + l15];

  int tteC[4];
#pragma unroll
  for (int r = 0; r < 4; ++r) tteC[r] = tte[b0 + 4 * lg + r];
  const int tteS = tte[b0 + (tid >> 5)];
  int tmax = 0;
  for (int i = 0; i < 16; ++i) tmax = max(tmax, tte[b0 + i]);

  // gi base for (block, wave, lane); per-t stride = 64*8*6*256 bf16
  const __bf16* gib = gi + ((size_t)blockIdx.x * 8 + w) * 6 * 256 + (lg * 16 + l15) * 4;
  bf16x4 g[6];
#pragma unroll
  for (int tile = 0; tile < 6; ++tile) g[tile] = *(const bf16x4*)(gib + tile * 256);

  __syncthreads();

#pragma unroll 1
  for (int t = 0; t < tmax; ++t) {
    const int p = t & 1;
    f32x4 acc[6];
#pragma unroll
    for (int tile = 0; tile < 4; ++tile)
#pragma unroll
      for (int r = 0; r < 4; ++r) acc[tile][r] = (float)g[tile][r];
#pragma unroll
    for (int r = 0; r < 4; ++r) { acc[4][r] = bhn[0]; acc[5][r] = bhn[1]; }
    const bf16x4 gn0 = g[4], gn1 = g[5];

    // prefetch next step's gi (consumed at next acc-init; hidden under MFMAs)
    const int tp = min(t + 1, 255);
    const __bf16* gp = gib + (size_t)tp * 786432;
#pragma unroll
    for (int tile = 0; tile < 6; ++tile) g[tile] = *(const bf16x4*)(gp + tile * 256);

    // gh = h_t @ W_hh^T, weights in registers, A-frags from LDS
#pragma unroll
    for (int kt = 0; kt < 8; ++kt) {
      const bf16x8 hf8 = *(const bf16x8*)&hbuf[p][l15][kt * 32 + kofs];
#pragma unroll
      for (int tile = 0; tile < 6; ++tile) acc[tile] = MFMA16(hf8, wfr[tile][kt], acc[tile]);
    }

    // gates + h update (C-layout: row = 4*lg+r, col = w*32+hf*16+l15)
#pragma unroll
    for (int hf = 0; hf < 2; ++hf) {
      const int colL = w * 32 + hf * 16 + l15;
#pragma unroll
      for (int r = 0; r < 4; ++r) {
        const int row = 4 * lg + r;
        const float rg = sigm(acc[0 + hf][r]);
        const float zg = sigm(acc[2 + hf][r]);
        const float gin = hf ? (float)gn1[r] : (float)gn0[r];
        const float ng = tanh_f(gin + rg * acc[4 + hf][r]);
        const float hold = (float)hbuf[p][row][colL];
        const float hnew = zg * (hold - ng) + ng;
        const float hw = (t < tteC[r]) ? hnew : hold;
        hbuf[p ^ 1][row][colL] = (__bf16)hw;
      }
    }
    __syncthreads();
    // hidden store (active rows only; inactive pre-zeroed by memset)
    if (t < tteS) {
      const int row = tid >> 5, seg = tid & 31;
      uint4 v = *(const uint4*)&hbuf[p ^ 1][row][seg * 8];
      *(uint4*)(hid + ((size_t)(b0 + row) * L_ + t) * H_ + seg * 8) = v;
    }
  }
}

// ---- out = mask ? hid@W_out^T + b_out : 0  (writes zeros; no d_out memset) ----
__global__ __launch_bounds__(512, 2) void out_gemm_kernel(
    const __bf16* __restrict__ hid, const __bf16* __restrict__ wout,
    const float* __restrict__ b_out, const int* __restrict__ tte,
    float* __restrict__ out) {
  const int tid = threadIdx.x;
  const int lane = tid & 63, w = tid >> 6;
  const int l15 = lane & 15, lg = lane >> 4, kofs = lg * 8;
  const int row0 = blockIdx.x * 128 + w * 16;  // flattened (b,t) row
  const int bI = row0 >> 8;                    // single b per block (128 | 256)
  const int tteB = tte[bI];
  const int tbase = row0 & 255;

  f32x4 acc[8];
#pragma unroll
  for (int tile = 0; tile < 8; ++tile) { acc[tile][0] = 0; acc[tile][1] = 0; acc[tile][2] = 0; acc[tile][3] = 0; }
#pragma unroll
  for (int kt = 0; kt < 8; ++kt) {
    const bf16x8 af = *(const bf16x8*)(hid + (size_t)(row0 + l15) * H_ + kt * 32 + kofs);
#pragma unroll
    for (int tile = 0; tile < 8; ++tile)
      acc[tile] = MFMA16(af, ld8(wout + (size_t)(tile * 16 + l15) * H_ + kt * 32 + kofs), acc[tile]);
  }
#pragma unroll
  for (int tile = 0; tile < 8; ++tile) {
    const float bo = b_out[tile * 16 + l15];
#pragma unroll
    for (int r = 0; r < 4; ++r) {
      const int R = row0 + 4 * lg + r;
      const int t = tbase + 4 * lg + r;
      out[(size_t)R * F_ + tile * 16 + l15] = (t < tteB) ? acc[tile][r] + bo : 0.f;
    }
  }
}

// ---- decoder: attention (MFMA scores), softmax, context, MLP, final softmax ----
__global__ __launch_bounds__(256, 2) void decoder_kernel(
    const float* __restrict__ x, const int* __restrict__ tte,
    const __bf16* __restrict__ hid, const __bf16* __restrict__ wa_t,
    const float* __restrict__ va, const float* __restrict__ Ua,
    const float* __restrict__ W1, const float* __restrict__ b1,
    const float* __restrict__ W2, const float* __restrict__ b2,
    float* __restrict__ fht) {
  __shared__ float last_s[128], u_s[128], s_s[256], alpha_s[256], ctx_s[256], z1_s[256], f512[512];
  const int tid = threadIdx.x;
  const int b = blockIdx.x;
  const int tb = tte[b];
  if (tid < 128) last_s[tid] = x[((size_t)b * L_ + tb) * F_ + tid];
  __syncthreads();
  if (tid < 128) {
    float a = 0.f;
    for (int f = 0; f < 128; ++f) a += last_s[f] * Ua[f * 128 + tid];
    u_s[tid] = a;
  }
  __syncthreads();
  const int lane = tid & 63, w = tid >> 6, l15 = lane & 15, lg = lane >> 4, kofs = lg * 8;
#pragma unroll 1
  for (int mi = 0; mi < 4; ++mi) {
    const int mtile = w * 4 + mi;
    const int trow = mtile * 16 + l15;
    f32x4 sacc[8];
#pragma unroll
    for (int ct = 0; ct < 8; ++ct) { sacc[ct][0] = 0; sacc[ct][1] = 0; sacc[ct][2] = 0; sacc[ct][3] = 0; }
#pragma unroll
    for (int kt = 0; kt < 8; ++kt) {
      bf16x8 af = *(const bf16x8*)&hid[((size_t)b * L_ + trow) * H_ + kt * 32 + kofs];
#pragma unroll
      for (int ct = 0; ct < 8; ++ct) {
        bf16x8 bf = *(const bf16x8*)&wa_t[(size_t)(ct * 16 + l15) * 256 + kt * 32 + kofs];
        sacc[ct] = MFMA16(af, bf, sacc[ct]);
      }
    }
    float sp[4] = {0, 0, 0, 0};
#pragma unroll
    for (int ct = 0; ct < 8; ++ct) {
      int a = ct * 16 + l15;
      float ua = u_s[a], vv = va[a];
#pragma unroll
      for (int r = 0; r < 4; ++r) sp[r] += tanh_f(sacc[ct][r] + ua) * vv;
    }
#pragma unroll
    for (int r = 0; r < 4; ++r) {
      sp[r] += __shfl_xor(sp[r], 1);
      sp[r] += __shfl_xor(sp[r], 2);
      sp[r] += __shfl_xor(sp[r], 4);
      sp[r] += __shfl_xor(sp[r], 8);
    }
    if (l15 == 0) {
#pragma unroll
      for (int r = 0; r < 4; ++r) s_s[mtile * 16 + 4 * lg + r] = sp[r];
    }
  }
  __syncthreads();
  float m = -1e30f;
  for (int i = 0; i < 256; ++i) m = fmaxf(m, s_s[i]);
  float e = __expf(s_s[tid] - m);
  alpha_s[tid] = e;
  __syncthreads();
  float den = 0.f;
  for (int i = 0; i < 256; ++i) den += alpha_s[i];
  const float inv = 1.f / den;
  float cacc = 0.f;
  for (int t = 0; t < 256; ++t)
    cacc += alpha_s[t] * (float)hid[((size_t)b * L_ + t) * H_ + tid];
  ctx_s[tid] = cacc * inv;
  __syncthreads();
  float a1 = b1[tid];
  for (int k = 0; k < 256; ++k) a1 += ctx_s[k] * W1[k * 256 + tid];
  for (int k = 0; k < 128; ++k) a1 += last_s[k] * W1[(256 + k) * 256 + tid];
  z1_s[tid] = fmaxf(a1, 0.f);
  __syncthreads();
  float o0 = b2[tid], o1 = b2[tid + 256];
  for (int k = 0; k < 256; ++k) {
    float zv = z1_s[k];
    o0 += zv * W2[k * 512 + tid];
    o1 += zv * W2[k * 512 + tid + 256];
  }
  f512[tid] = o0; f512[tid + 256] = o1;
  __syncthreads();
  float m2 = -1e30f;
  for (int i = 0; i < 512; ++i) m2 = fmaxf(m2, f512[i]);
  __syncthreads();
  float e0 = __expf(o0 - m2), e1 = __expf(o1 - m2);
  f512[tid] = e0; f512[tid + 256] = e1;
  __syncthreads();
  float d2 = 0.f;
  for (int i = 0; i < 512; ++i) d2 += f512[i];
  const float inv2 = 1.f / d2;
  fht[(size_t)b * 512 + tid] = e0 * inv2;
  fht[(size_t)b * 512 + tid + 256] = e1 * inv2;
}

extern "C" void kernel_launch(void* const* d_in, const int* in_sizes, int n_in,
                              void* d_out, int out_size, void* d_ws, size_t ws_size,
                              hipStream_t stream) {
  const float* x = (const float*)d_in[0];
  const int* tte = (const int*)d_in[1];
  const float* W_ih = (const float*)d_in[2];
  const float* W_hh = (const float*)d_in[3];
  const float* b_ih = (const float*)d_in[4];
  const float* b_hh = (const float*)d_in[5];
  const float* W_out = (const float*)d_in[6];
  const float* b_out = (const float*)d_in[7];
  const float* Wa = (const float*)d_in[8];
  const float* Ua = (const float*)d_in[9];
  const float* va = (const float*)d_in[10];
  const float* W1 = (const float*)d_in[11];
  const float* b1 = (const float*)d_in[12];
  const float* W2 = (const float*)d_in[13];
  const float* b2 = (const float*)d_in[14];

  char* ws = (char*)d_ws;
  __bf16* wih = (__bf16*)(ws + 0);            // 768*128*2   = 196608
  __bf16* whh = (__bf16*)(ws + 196608);       // 768*256*2   = 393216
  __bf16* wout = (__bf16*)(ws + 589824);      // 128*256*2   = 65536
  __bf16* wa_t = (__bf16*)(ws + 655360);      // 128*256*2   = 65536
  __bf16* hid = (__bf16*)(ws + 1048576);      // 1024*256*256*2 = 134217728
  __bf16* gi = (__bf16*)(ws + 135266304);     // 256*64*8*6*256*2 = 402653184

  float* out = (float*)d_out;
  float* fht = out + (size_t)33554432;

  hipMemsetAsync(hid, 0, (size_t)134217728, stream);   // zero hidden past tte
  cvt_kernel<<<1408, 256, 0, stream>>>(W_ih, W_hh, W_out, Wa, wih, whh, wout, wa_t);
  gi_gemm_kernel<<<1024, 512, 0, stream>>>(x, b_ih, b_hh, wih, gi);
  gru2_kernel<<<64, 512, 0, stream>>>(tte, b_hh, whh, gi, hid);
  out_gemm_kernel<<<2048, 512, 0, stream>>>(hid, wout, b_out, tte, out);
  decoder_kernel<<<1024, 256, 0, stream>>>(x, tte, hid, wa_t, va, Ua, W1, b1, W2, b2, fht);
}

// Round 3
// 1307.422 us; speedup vs baseline: 2.9734x; 1.0439x over previous
//
#include <hip/hip_runtime.h>

// B=1024, L=256, F=128, H=256, 3H=768, A=128, CH=256, OUT=512
#define B_ 1024
#define L_ 256
#define F_ 128
#define H_ 256

typedef __bf16 bf16x8 __attribute__((ext_vector_type(8)));
typedef __bf16 bf16x4 __attribute__((ext_vector_type(4)));
typedef float f32x4 __attribute__((ext_vector_type(4)));

#define MFMA16(a, b, c) __builtin_amdgcn_mfma_f32_16x16x32_bf16((a), (b), (c), 0, 0, 0)

__device__ __forceinline__ float sigm(float x) { return 1.f / (1.f + __expf(-x)); }
__device__ __forceinline__ float tanh_f(float x) {
  float ax = fabsf(x);
  float e = __expf(-2.f * ax);
  float r = (1.f - e) / (1.f + e);
  return copysignf(r, x);
}
__device__ __forceinline__ bf16x8 ld8(const __bf16* p) { return *(const bf16x8*)p; }
__device__ __forceinline__ float wave_max(float v) {
#pragma unroll
  for (int d = 1; d < 64; d <<= 1) v = fmaxf(v, __shfl_xor(v, d));
  return v;
}
__device__ __forceinline__ float wave_sum(float v) {
#pragma unroll
  for (int d = 1; d < 64; d <<= 1) v += __shfl_xor(v, d);
  return v;
}

// ---- weight conversion: f32 -> bf16 (Wa also transposed to [A][H]) ----
__global__ void cvt_kernel(const float* __restrict__ wih_f, const float* __restrict__ whh_f,
                           const float* __restrict__ wout_f, const float* __restrict__ wa_f,
                           __bf16* __restrict__ wih, __bf16* __restrict__ whh,
                           __bf16* __restrict__ wout, __bf16* __restrict__ wa_t) {
  int i = blockIdx.x * 256 + threadIdx.x;
  if (i < 98304) wih[i] = (__bf16)wih_f[i];                           // [768][128]
  else if (i < 294912) whh[i - 98304] = (__bf16)whh_f[i - 98304];     // [768][256]
  else if (i < 327680) wout[i - 294912] = (__bf16)wout_f[i - 294912]; // [128][256]
  else if (i < 360448) {                                              // Wa[k][a] -> wa_t[a][k]
    int j = i - 327680;
    int a = j >> 8, k = j & 255;
    wa_t[j] = (__bf16)wa_f[k * 128 + a];
  }
}

// ---- gi precompute: gi[b,t,:] = x[b,t]@W_ih^T (+ folded biases), bf16,
// stored in MFMA C-fragment layout: chunk = ((t*64+bblk)*8+w)*6+tile,
// within chunk: (lg*16+l15)*4 + r  (4 rows per lane, 8B coalesced). ----
__global__ __launch_bounds__(512, 2) void gi_gemm_kernel(
    const float* __restrict__ x, const float* __restrict__ b_ih,
    const float* __restrict__ b_hh, const __bf16* __restrict__ wih,
    const int* __restrict__ tte, __bf16* __restrict__ gi) {
  const int tid = threadIdx.x;
  const int lane = tid & 63, w = tid >> 6;
  const int l15 = lane & 15, lg = lane >> 4, kofs = lg * 8;
  const int bblk = blockIdx.x & 63, tgrp = blockIdx.x >> 6;
  const int b0 = bblk * 16;

  int tmaxB = 0;
  for (int i = 0; i < 16; ++i) tmaxB = max(tmaxB, tte[b0 + i]);
  if (tgrp * 16 > tmaxB) return;   // slabs t<=tmaxB are consumed (incl. prefetch)

  bf16x8 wf[6][4];
  float bias[6];
#pragma unroll
  for (int tile = 0; tile < 6; ++tile) {
    const int gate = tile >> 1;
    const int c = w * 32 + (tile & 1) * 16 + l15;
    const int col = gate * 256 + c;
#pragma unroll
    for (int kt = 0; kt < 4; ++kt) wf[tile][kt] = ld8(wih + (size_t)col * 128 + kt * 32 + kofs);
    bias[tile] = (gate == 0) ? b_ih[c] + b_hh[c]
               : (gate == 1) ? b_ih[256 + c] + b_hh[256 + c]
                             : b_ih[512 + c];
  }

#pragma unroll 1
  for (int ti = 0; ti < 16; ++ti) {
    const int t = tgrp * 16 + ti;
    if (t > tmaxB) break;
    const float* xb = x + ((size_t)(b0 + l15) * L_ + t) * F_ + kofs;
    bf16x8 xfr[4];
#pragma unroll
    for (int kt = 0; kt < 4; ++kt) {
      float4 a = *(const float4*)(xb + kt * 32);
      float4 b = *(const float4*)(xb + kt * 32 + 4);
      xfr[kt][0] = (__bf16)a.x; xfr[kt][1] = (__bf16)a.y;
      xfr[kt][2] = (__bf16)a.z; xfr[kt][3] = (__bf16)a.w;
      xfr[kt][4] = (__bf16)b.x; xfr[kt][5] = (__bf16)b.y;
      xfr[kt][6] = (__bf16)b.z; xfr[kt][7] = (__bf16)b.w;
    }
    f32x4 acc[6];
#pragma unroll
    for (int tile = 0; tile < 6; ++tile) {
      acc[tile][0] = bias[tile]; acc[tile][1] = bias[tile];
      acc[tile][2] = bias[tile]; acc[tile][3] = bias[tile];
    }
#pragma unroll
    for (int kt = 0; kt < 4; ++kt)
#pragma unroll
      for (int tile = 0; tile < 6; ++tile)
        acc[tile] = MFMA16(xfr[kt], wf[tile][kt], acc[tile]);

    const size_t chunk = (((size_t)t * 64 + bblk) * 8 + w) * 6;
#pragma unroll
    for (int tile = 0; tile < 6; ++tile) {
      bf16x4 pk;
      pk[0] = (__bf16)acc[tile][0]; pk[1] = (__bf16)acc[tile][1];
      pk[2] = (__bf16)acc[tile][2]; pk[3] = (__bf16)acc[tile][3];
      *(bf16x4*)(gi + (chunk + tile) * 256 + (lg * 16 + l15) * 4) = pk;
    }
  }
}

// ---- recurrence: W_hh register-resident, FORCED:
//  - amdgpu_waves_per_eu(2,2) pins allocator budget to 256 VGPR (2 waves/EU)
//  - opaque asm on each fragment blocks load rematerialization into the loop ----
__global__ __launch_bounds__(512) __attribute__((amdgpu_waves_per_eu(2, 2)))
void gru2_kernel(
    const int* __restrict__ tte, const float* __restrict__ b_hh,
    const __bf16* __restrict__ whh, const __bf16* __restrict__ gi,
    __bf16* __restrict__ hid) {
  __shared__ __bf16 hbuf[2][16][264];
  const int tid = threadIdx.x;
  const int lane = tid & 63, w = tid >> 6;
  const int l15 = lane & 15, lg = lane >> 4, kofs = lg * 8;
  const int b0 = blockIdx.x * 16;

  for (int i = tid; i < 2 * 16 * 264; i += 512) ((__bf16*)hbuf)[i] = (__bf16)0.f;

  bf16x8 wfr[6][8];
#pragma unroll
  for (int tile = 0; tile < 6; ++tile) {
    const int col = (tile >> 1) * 256 + w * 32 + (tile & 1) * 16 + l15;
#pragma unroll
    for (int kt = 0; kt < 8; ++kt) wfr[tile][kt] = ld8(whh + (size_t)col * 256 + kt * 32 + kofs);
  }
#pragma unroll
  for (int tile = 0; tile < 6; ++tile)
#pragma unroll
    for (int kt = 0; kt < 8; ++kt)
      asm volatile("" : "+v"(wfr[tile][kt]));   // opaque: keep resident, no remat

  float bhn[2];
#pragma unroll
  for (int hf = 0; hf < 2; ++hf) bhn[hf] = b_hh[512 + w * 32 + hf * 16 + l15];

  int tteC[4];
#pragma unroll
  for (int r = 0; r < 4; ++r) tteC[r] = tte[b0 + 4 * lg + r];
  const int tteS = tte[b0 + (tid >> 5)];
  int tmax = 0;
  for (int i = 0; i < 16; ++i) tmax = max(tmax, tte[b0 + i]);

  // gi base for (block, wave, lane); per-t stride = 64*8*6*256 bf16
  const __bf16* gib = gi + ((size_t)blockIdx.x * 8 + w) * 6 * 256 + (lg * 16 + l15) * 4;
  bf16x4 g[6];
#pragma unroll
  for (int tile = 0; tile < 6; ++tile) g[tile] = *(const bf16x4*)(gib + tile * 256);

  __syncthreads();

#pragma unroll 1
  for (int t = 0; t < tmax; ++t) {
    const int p = t & 1;
    f32x4 acc[6];
#pragma unroll
    for (int tile = 0; tile < 4; ++tile)
#pragma unroll
      for (int r = 0; r < 4; ++r) acc[tile][r] = (float)g[tile][r];
#pragma unroll
    for (int r = 0; r < 4; ++r) { acc[4][r] = bhn[0]; acc[5][r] = bhn[1]; }
    const bf16x4 gn0 = g[4], gn1 = g[5];

    // prefetch next step's gi (consumed at next acc-init; hidden under MFMAs)
    const int tp = min(t + 1, 255);
    const __bf16* gp = gib + (size_t)tp * 786432;
#pragma unroll
    for (int tile = 0; tile < 6; ++tile) g[tile] = *(const bf16x4*)(gp + tile * 256);

    // gh = h_t @ W_hh^T, weights in registers, A-frags from LDS
#pragma unroll
    for (int kt = 0; kt < 8; ++kt) {
      const bf16x8 hf8 = *(const bf16x8*)&hbuf[p][l15][kt * 32 + kofs];
#pragma unroll
      for (int tile = 0; tile < 6; ++tile) acc[tile] = MFMA16(hf8, wfr[tile][kt], acc[tile]);
    }

    // gates + h update (C-layout: row = 4*lg+r, col = w*32+hf*16+l15)
#pragma unroll
    for (int hf = 0; hf < 2; ++hf) {
      const int colL = w * 32 + hf * 16 + l15;
#pragma unroll
      for (int r = 0; r < 4; ++r) {
        const int row = 4 * lg + r;
        const float rg = sigm(acc[0 + hf][r]);
        const float zg = sigm(acc[2 + hf][r]);
        const float gin = hf ? (float)gn1[r] : (float)gn0[r];
        const float ng = tanh_f(gin + rg * acc[4 + hf][r]);
        const float hold = (float)hbuf[p][row][colL];
        const float hnew = zg * (hold - ng) + ng;
        const float hw = (t < tteC[r]) ? hnew : hold;
        hbuf[p ^ 1][row][colL] = (__bf16)hw;
      }
    }
    __syncthreads();
    // hidden store (active rows only; inactive pre-zeroed by memset)
    if (t < tteS) {
      const int row = tid >> 5, seg = tid & 31;
      uint4 v = *(const uint4*)&hbuf[p ^ 1][row][seg * 8];
      *(uint4*)(hid + ((size_t)(b0 + row) * L_ + t) * H_ + seg * 8) = v;
    }
  }
}

// ---- out = mask ? hid@W_out^T + b_out : 0  (writes zeros; no d_out memset) ----
__global__ __launch_bounds__(512, 2) void out_gemm_kernel(
    const __bf16* __restrict__ hid, const __bf16* __restrict__ wout,
    const float* __restrict__ b_out, const int* __restrict__ tte,
    float* __restrict__ out) {
  const int tid = threadIdx.x;
  const int lane = tid & 63, w = tid >> 6;
  const int l15 = lane & 15, lg = lane >> 4, kofs = lg * 8;
  const int row0 = blockIdx.x * 128 + w * 16;  // flattened (b,t) row
  const int bI = row0 >> 8;                    // single b per block (128 | 256)
  const int tteB = tte[bI];
  const int tbase = row0 & 255;

  f32x4 acc[8];
#pragma unroll
  for (int tile = 0; tile < 8; ++tile) { acc[tile][0] = 0; acc[tile][1] = 0; acc[tile][2] = 0; acc[tile][3] = 0; }
#pragma unroll
  for (int kt = 0; kt < 8; ++kt) {
    const bf16x8 af = *(const bf16x8*)(hid + (size_t)(row0 + l15) * H_ + kt * 32 + kofs);
#pragma unroll
    for (int tile = 0; tile < 8; ++tile)
      acc[tile] = MFMA16(af, ld8(wout + (size_t)(tile * 16 + l15) * H_ + kt * 32 + kofs), acc[tile]);
  }
#pragma unroll
  for (int tile = 0; tile < 8; ++tile) {
    const float bo = b_out[tile * 16 + l15];
#pragma unroll
    for (int r = 0; r < 4; ++r) {
      const int R = row0 + 4 * lg + r;
      const int t = tbase + 4 * lg + r;
      out[(size_t)R * F_ + tile * 16 + l15] = (t < tteB) ? acc[tile][r] + bo : 0.f;
    }
  }
}

// ---- decoder: attention (MFMA scores), softmax, context, MLP, final softmax ----
__global__ __launch_bounds__(256, 2) void decoder_kernel(
    const float* __restrict__ x, const int* __restrict__ tte,
    const __bf16* __restrict__ hid, const __bf16* __restrict__ wa_t,
    const float* __restrict__ va, const float* __restrict__ Ua,
    const float* __restrict__ W1, const float* __restrict__ b1,
    const float* __restrict__ W2, const float* __restrict__ b2,
    float* __restrict__ fht) {
  __shared__ float last_s[128], u_s[128], s_s[256], alpha_s[256], ctx_s[256], z1_s[256], red_s[8];
  const int tid = threadIdx.x;
  const int b = blockIdx.x;
  const int tb = tte[b];
  if (tid < 128) last_s[tid] = x[((size_t)b * L_ + tb) * F_ + tid];
  __syncthreads();
  if (tid < 128) {
    float a = 0.f;
    for (int f = 0; f < 128; ++f) a += last_s[f] * Ua[f * 128 + tid];
    u_s[tid] = a;
  }
  __syncthreads();
  const int lane = tid & 63, w = tid >> 6, l15 = lane & 15, lg = lane >> 4, kofs = lg * 8;
#pragma unroll 1
  for (int mi = 0; mi < 4; ++mi) {
    const int mtile = w * 4 + mi;
    const int trow = mtile * 16 + l15;
    f32x4 sacc[8];
#pragma unroll
    for (int ct = 0; ct < 8; ++ct) { sacc[ct][0] = 0; sacc[ct][1] = 0; sacc[ct][2] = 0; sacc[ct][3] = 0; }
#pragma unroll
    for (int kt = 0; kt < 8; ++kt) {
      bf16x8 af = *(const bf16x8*)&hid[((size_t)b * L_ + trow) * H_ + kt * 32 + kofs];
#pragma unroll
      for (int ct = 0; ct < 8; ++ct) {
        bf16x8 bf = *(const bf16x8*)&wa_t[(size_t)(ct * 16 + l15) * 256 + kt * 32 + kofs];
        sacc[ct] = MFMA16(af, bf, sacc[ct]);
      }
    }
    float sp[4] = {0, 0, 0, 0};
#pragma unroll
    for (int ct = 0; ct < 8; ++ct) {
      int a = ct * 16 + l15;
      float ua = u_s[a], vv = va[a];
#pragma unroll
      for (int r = 0; r < 4; ++r) sp[r] += tanh_f(sacc[ct][r] + ua) * vv;
    }
#pragma unroll
    for (int r = 0; r < 4; ++r) {
      sp[r] += __shfl_xor(sp[r], 1);
      sp[r] += __shfl_xor(sp[r], 2);
      sp[r] += __shfl_xor(sp[r], 4);
      sp[r] += __shfl_xor(sp[r], 8);
    }
    if (l15 == 0) {
#pragma unroll
      for (int r = 0; r < 4; ++r) s_s[mtile * 16 + 4 * lg + r] = sp[r];
    }
  }
  __syncthreads();
  // softmax over 256 scores: shfl-based block reduction
  const float sv = s_s[tid];
  float wm = wave_max(sv);
  if (lane == 0) red_s[w] = wm;
  __syncthreads();
  const float m = fmaxf(fmaxf(red_s[0], red_s[1]), fmaxf(red_s[2], red_s[3]));
  const float e = __expf(sv - m);
  alpha_s[tid] = e;
  float wsum = wave_sum(e);
  if (lane == 0) red_s[4 + w] = wsum;
  __syncthreads();
  const float inv = 1.f / (red_s[4] + red_s[5] + red_s[6] + red_s[7]);
  float cacc = 0.f;
  for (int t = 0; t < 256; ++t)
    cacc += alpha_s[t] * (float)hid[((size_t)b * L_ + t) * H_ + tid];
  ctx_s[tid] = cacc * inv;
  __syncthreads();
  float a1 = b1[tid];
  for (int k = 0; k < 256; ++k) a1 += ctx_s[k] * W1[k * 256 + tid];
  for (int k = 0; k < 128; ++k) a1 += last_s[k] * W1[(256 + k) * 256 + tid];
  z1_s[tid] = fmaxf(a1, 0.f);
  __syncthreads();
  float o0 = b2[tid], o1 = b2[tid + 256];
  for (int k = 0; k < 256; ++k) {
    float zv = z1_s[k];
    o0 += zv * W2[k * 512 + tid];
    o1 += zv * W2[k * 512 + tid + 256];
  }
  // final softmax over 512 (each thread holds 2 values)
  float wm2 = wave_max(fmaxf(o0, o1));
  if (lane == 0) red_s[w] = wm2;
  __syncthreads();
  const float m2 = fmaxf(fmaxf(red_s[0], red_s[1]), fmaxf(red_s[2], red_s[3]));
  const float e0 = __expf(o0 - m2), e1 = __expf(o1 - m2);
  float ws2 = wave_sum(e0 + e1);
  if (lane == 0) red_s[4 + w] = ws2;
  __syncthreads();
  const float inv2 = 1.f / (red_s[4] + red_s[5] + red_s[6] + red_s[7]);
  fht[(size_t)b * 512 + tid] = e0 * inv2;
  fht[(size_t)b * 512 + tid + 256] = e1 * inv2;
}

extern "C" void kernel_launch(void* const* d_in, const int* in_sizes, int n_in,
                              void* d_out, int out_size, void* d_ws, size_t ws_size,
                              hipStream_t stream) {
  const float* x = (const float*)d_in[0];
  const int* tte = (const int*)d_in[1];
  const float* W_ih = (const float*)d_in[2];
  const float* W_hh = (const float*)d_in[3];
  const float* b_ih = (const float*)d_in[4];
  const float* b_hh = (const float*)d_in[5];
  const float* W_out = (const float*)d_in[6];
  const float* b_out = (const float*)d_in[7];
  const float* Wa = (const float*)d_in[8];
  const float* Ua = (const float*)d_in[9];
  const float* va = (const float*)d_in[10];
  const float* W1 = (const float*)d_in[11];
  const float* b1 = (const float*)d_in[12];
  const float* W2 = (const float*)d_in[13];
  const float* b2 = (const float*)d_in[14];

  char* ws = (char*)d_ws;
  __bf16* wih = (__bf16*)(ws + 0);            // 768*128*2   = 196608
  __bf16* whh = (__bf16*)(ws + 196608);       // 768*256*2   = 393216
  __bf16* wout = (__bf16*)(ws + 589824);      // 128*256*2   = 65536
  __bf16* wa_t = (__bf16*)(ws + 655360);      // 128*256*2   = 65536
  __bf16* hid = (__bf16*)(ws + 1048576);      // 1024*256*256*2 = 134217728
  __bf16* gi = (__bf16*)(ws + 135266304);     // 256*64*8*6*256*2 = 402653184

  float* out = (float*)d_out;
  float* fht = out + (size_t)33554432;

  hipMemsetAsync(hid, 0, (size_t)134217728, stream);   // zero hidden past tte
  cvt_kernel<<<1408, 256, 0, stream>>>(W_ih, W_hh, W_out, Wa, wih, whh, wout, wa_t);
  gi_gemm_kernel<<<1024, 512, 0, stream>>>(x, b_ih, b_hh, wih, tte, gi);
  gru2_kernel<<<64, 512, 0, stream>>>(tte, b_hh, whh, gi, hid);
  out_gemm_kernel<<<2048, 512, 0, stream>>>(hid, wout, b_out, tte, out);
  decoder_kernel<<<1024, 256, 0, stream>>>(x, tte, hid, wa_t, va, Ua, W1, b1, W2, b2, fht);
}